// Round 12
// baseline (405.242 us; speedup 1.0000x reference)
//
#include <hip/hip_runtime.h>
#include <math.h>

#pragma clang fp contract(off)

// Problem constants (match reference)
#define PNUM 136500      // sum of f*f
#define HPNUM 68250      // PNUM/2 (exact)
#define BNUM 16
#define TOPK 5000
#define CAP 8192         // candidate capacity per image (power of 2 for bitonic)
#define NB2 1024         // histogram window buckets (covers ord16 of (0.01, 1.0))
#define B2BASE 0xBC00u   // window base: f2ord(0.01)>>16 = 0xBC23 >= 0xBC00
#define NWORDS 79        // ceil(5000/64)
#define TRIW 202240      // triangular words per image: 64 * (79+78+...+1)
#define MASK_PER_IMG ((size_t)TRIW * 8)   // 1,617,920 B
#define GSTRIDE 32       // gcnt padding: 32 u32 = 128 B per image

// Workspace layout (bytes). Boxes live at the front; hist/cut/gcnt/keys are
// DEAD after k_decode, so the mask region overlaps them.
#define OFF_SC    ((size_t)0)
#define OFF_X1    (OFF_SC + 320000)
#define OFF_Y1    (OFF_X1 + 320000)
#define OFF_X2    (OFF_Y1 + 320000)
#define OFF_Y2    (OFF_X2 + 320000)
#define OFF_AREA  (OFF_Y2 + 320000)       // ends at 1,920,000
#define OFF_MASK  ((size_t)1920000)
#define OFF_HIST  ((size_t)1920000)       // overlaps mask (dead before k_mask)
#define OFF_CUT   (OFF_HIST + 65536)      // hist = 16*1024*4 = 65536 B
#define OFF_GCNT  (OFF_CUT + 64)
#define OFF_KEYS  (OFF_GCNT + 2048)

__device__ __forceinline__ unsigned f2ord(float f) {
    unsigned u = __float_as_uint(f);
    return (u & 0x80000000u) ? ~u : (u | 0x80000000u);
}
__device__ __forceinline__ float ord2f(unsigned o) {
    unsigned u = (o & 0x80000000u) ? (o ^ 0x80000000u) : ~o;
    return __uint_as_float(u);
}
// word offset of block t's slab within an image's triangular mask (transposed:
// word w, row r at tri_base2(t) + (w-t)*64 + r)
__device__ __forceinline__ int tri_base2(int t) {
    return 64 * (79 * t - ((t * (t - 1)) >> 1));
}

// K1: per-image histogram over the 1024-bucket window in LDS, then one
// contiguous atomic merge per block.
__global__ void __launch_bounds__(256) k_hist(const float* __restrict__ conf,
                                              unsigned* __restrict__ hist) {
    __shared__ unsigned lh[NB2];
    int img = blockIdx.y;
    for (int i = threadIdx.x; i < NB2; i += 256) lh[i] = 0;
    __syncthreads();
    const float4* src = (const float4*)(conf + (size_t)img * PNUM * 2);
    int stride = gridDim.x * 256;
    for (int q = blockIdx.x * 256 + threadIdx.x; q < HPNUM; q += stride) {
        float4 v = src[q];
        if (v.y > 0.01f) atomicAdd(&lh[(f2ord(v.y) >> 16) - B2BASE], 1u);
        if (v.w > 0.01f) atomicAdd(&lh[(f2ord(v.w) >> 16) - B2BASE], 1u);
    }
    __syncthreads();
    unsigned* h = hist + (size_t)img * NB2;
    for (int i = threadIdx.x; i < NB2; i += 256) {
        unsigned c = lh[i];
        if (c) atomicAdd(&h[i], c);
    }
}

// K2: find cutoff (absolute 16-bit bucket) so count(bucket >= cut) >= TOPK
__global__ void __launch_bounds__(256) k_cutoff(const unsigned* __restrict__ hist,
                                                unsigned* __restrict__ cut) {
    __shared__ unsigned csum[256];
    int img = blockIdx.x;
    int t = threadIdx.x;
    const unsigned* h = hist + (size_t)img * NB2;
    unsigned s = 0;
    for (int b = 0; b < 4; ++b) s += h[t * 4 + b];
    csum[t] = s;
    __syncthreads();
    if (t == 0) {
        unsigned acc = 0, before = 0;
        int c = -1;
        for (int cc = 255; cc >= 0; --cc) {
            if (acc + csum[cc] >= (unsigned)TOPK) { c = cc; before = acc; break; }
            acc += csum[cc];
        }
        unsigned cutb = B2BASE;            // fallback: take all valid
        if (c >= 0) {
            unsigned s2 = before;
            cutb = B2BASE + (unsigned)c * 4u;
            for (int b = c * 4 + 3; b >= c * 4; --b) {
                s2 += h[b];
                if (s2 >= (unsigned)TOPK) { cutb = B2BASE + (unsigned)b; break; }
            }
        }
        cut[img] = cutb;
    }
}

// K3: gather candidate keys (ord<<32)|~p for buckets >= cutoff.
__global__ void __launch_bounds__(256) k_gather(
        const float* __restrict__ conf, const unsigned* __restrict__ cut,
        unsigned* __restrict__ gcnt, unsigned long long* __restrict__ keys) {
    __shared__ unsigned wbase[4];
    __shared__ unsigned bbase;
    int q = blockIdx.x * 256 + threadIdx.x;
    int img = blockIdx.y;
    int lane = threadIdx.x & 63, wid = threadIdx.x >> 6;
    unsigned cutb = cut[img];
    bool c0 = false, c1 = false;
    unsigned o0 = 0, o1 = 0;
    int p0 = 0, p1 = 0;
    if (q < HPNUM) {
        float4 v = ((const float4*)(conf + (size_t)img * PNUM * 2))[q];
        p0 = 2 * q; p1 = 2 * q + 1;
        if (v.y > 0.01f) { o0 = f2ord(v.y); c0 = (o0 >> 16) >= cutb; }
        if (v.w > 0.01f) { o1 = f2ord(v.w); c1 = (o1 >> 16) >= cutb; }
    }
    unsigned long long b0 = __ballot(c0), b1 = __ballot(c1);
    if (lane == 0) wbase[wid] = (unsigned)(__popcll(b0) + __popcll(b1));
    __syncthreads();
    if (threadIdx.x == 0) {
        unsigned t0 = wbase[0], t1 = wbase[1], t2 = wbase[2], t3 = wbase[3];
        unsigned tot = t0 + t1 + t2 + t3;
        unsigned base = tot ? atomicAdd(&gcnt[(size_t)img * GSTRIDE], tot) : 0u;
        bbase = base;
        wbase[0] = 0; wbase[1] = t0; wbase[2] = t0 + t1; wbase[3] = t0 + t1 + t2;
    }
    __syncthreads();
    unsigned mybase = bbase + wbase[wid];
    unsigned long long lt = (lane == 0) ? 0ull : ((1ull << lane) - 1ull);
    if (c0) {
        unsigned pos = mybase + (unsigned)__popcll(b0 & lt);
        if (pos < (unsigned)CAP)
            keys[(size_t)img * CAP + pos] =
                ((unsigned long long)o0 << 32) | (unsigned)(~(unsigned)p0);
    }
    if (c1) {
        unsigned pos = mybase + (unsigned)__popcll(b0) + (unsigned)__popcll(b1 & lt);
        if (pos < (unsigned)CAP)
            keys[(size_t)img * CAP + pos] =
                ((unsigned long long)o1 << 32) | (unsigned)(~(unsigned)p1);
    }
}

// ---- Multi-block bitonic sort of each image's 8192 keys (descending) ----

// K4a: stages k=2..2048 (all chunk-local). 4 chunks of 2048 per image.
__global__ void __launch_bounds__(1024) k_sloc1(
        unsigned long long* __restrict__ keys, const unsigned* __restrict__ gcnt) {
    __shared__ unsigned long long sk[2048];
    int img = blockIdx.x >> 2;
    int base = (blockIdx.x & 3) * 2048;
    int N = (int)min(gcnt[(size_t)img * GSTRIDE], (unsigned)CAP);
    unsigned long long* kp = keys + (size_t)img * CAP;
    int tid = threadIdx.x;
    for (int i = tid; i < 2048; i += 1024)
        sk[i] = (base + i < N) ? kp[base + i] : 0ull;
    __syncthreads();
    for (int k = 2; k <= 2048; k <<= 1) {
        for (int j = k >> 1; j > 0; j >>= 1) {
            int i = ((tid & ~(j - 1)) << 1) | (tid & (j - 1));
            int p = i | j;
            bool desc = (((base + i) & k) == 0);
            unsigned long long a = sk[i], b = sk[p];
            bool sw = desc ? (a < b) : (a > b);
            if (sw) { sk[i] = b; sk[p] = a; }
            __syncthreads();
        }
    }
    for (int i = tid; i < 2048; i += 1024) kp[base + i] = sk[i];
}

// K4b: stage k=4096 complete (j=2048..1). 2 half-spans of 4096 per image.
__global__ void __launch_bounds__(1024) k_sloc2(unsigned long long* __restrict__ keys) {
    __shared__ unsigned long long sk[4096];
    int img = blockIdx.x >> 1;
    int base = (blockIdx.x & 1) * 4096;
    unsigned long long* kp = keys + (size_t)img * CAP + base;
    int tid = threadIdx.x;
    for (int i = tid; i < 4096; i += 1024) sk[i] = kp[i];
    __syncthreads();
    for (int j = 2048; j > 0; j >>= 1) {
        for (int t = tid; t < 2048; t += 1024) {
            int i = ((t & ~(j - 1)) << 1) | (t & (j - 1));
            int p = i | j;
            bool desc = (((base + i) & 4096) == 0);
            unsigned long long a = sk[i], b = sk[p];
            bool sw = desc ? (a < b) : (a > b);
            if (sw) { sk[i] = b; sk[p] = a; }
        }
        __syncthreads();
    }
    for (int i = tid; i < 4096; i += 1024) kp[i] = sk[i];
}

// K4c: stage k=8192 complete (j=4096..1, all descending). 1 block per image.
__global__ void __launch_bounds__(1024) k_sloc3(unsigned long long* __restrict__ keys) {
    __shared__ unsigned long long sk[CAP];
    unsigned long long* kp = keys + (size_t)blockIdx.x * CAP;
    int tid = threadIdx.x;
    for (int i = tid; i < CAP; i += 1024) sk[i] = kp[i];
    __syncthreads();
    for (int j = 4096; j > 0; j >>= 1) {
        for (int t = tid; t < 4096; t += 1024) {
            int i = ((t & ~(j - 1)) << 1) | (t & (j - 1));
            int p = i | j;
            unsigned long long a = sk[i], b = sk[p];
            if (a < b) { sk[i] = b; sk[p] = a; }     // always descending
        }
        __syncthreads();
    }
    for (int i = tid; i < CAP; i += 1024) kp[i] = sk[i];
}

// K4d: decode sorted top-5000 keys -> SC/X1/Y1/X2/Y2/AREA (fully parallel)
__global__ void __launch_bounds__(256) k_decode(
        const unsigned long long* __restrict__ keys,
        const float* __restrict__ loc, const float* __restrict__ pri,
        float* __restrict__ SC, float* __restrict__ X1, float* __restrict__ Y1,
        float* __restrict__ X2, float* __restrict__ Y2, float* __restrict__ AREA) {
    int gidx = blockIdx.x * 256 + threadIdx.x;
    if (gidx >= BNUM * TOPK) return;
    int img = gidx / TOPK;
    int r = gidx - img * TOPK;
    unsigned long long key = keys[(size_t)img * CAP + r];
    size_t o = (size_t)img * TOPK + r;
    if (key != 0ull) {
        unsigned ordv = (unsigned)(key >> 32);
        float s = ord2f(ordv);
        unsigned p = ~(unsigned)(key & 0xFFFFFFFFull);
        const float* lp = loc + ((size_t)img * PNUM + p) * 4;
        const float* pp = pri + (size_t)p * 4;
        float lx = lp[0], ly = lp[1], lw = lp[2], lh = lp[3];
        float px = pp[0], py = pp[1], pw = pp[2], ph = pp[3];
        float cx = px + (lx * 0.1f) * pw;
        float cy = py + (ly * 0.1f) * ph;
        float w = pw * expf(lw * 0.2f);
        float h = ph * expf(lh * 0.2f);
        float x1 = cx - w * 0.5f;
        float y1 = cy - h * 0.5f;
        float x2 = x1 + w;
        float y2 = y1 + h;
        SC[o] = s; X1[o] = x1; Y1[o] = y1; X2[o] = x2; Y2[o] = y2;
        AREA[o] = (x2 - x1) * (y2 - y1);
    } else {
        SC[o] = -1.0f; X1[o] = 0.f; Y1[o] = 0.f; X2[o] = 0.f; Y2[o] = 0.f;
        AREA[o] = 0.f;
    }
}

// K5a: transposed triangular suppression mask. Bit jj of word w (row i,
// block t=i>>6) = 1 iff row i (valid) suppresses j=w*64+jj (j>i, iou>0.3).
__global__ void __launch_bounds__(256) k_mask(
        const float* __restrict__ SC, const float* __restrict__ X1,
        const float* __restrict__ Y1, const float* __restrict__ X2,
        const float* __restrict__ Y2, const float* __restrict__ AREA,
        unsigned long long* __restrict__ mask, int img0) {
    int g = blockIdx.z;
    int cb = blockIdx.y;
    int bx = blockIdx.x;
    if ((cb + 1) * 64 <= bx * 256) return;   // whole block strictly sub-diagonal
    __shared__ float cx1[64], cy1[64], cx2[64], cy2[64], car[64];
    int img = img0 + g;
    int i = bx * 256 + threadIdx.x;
    int t = threadIdx.x;
    size_t ib = (size_t)img * TOPK;
    if (t < 64) {
        int j = cb * 64 + t;
        if (j < TOPK) {
            cx1[t] = X1[ib + j]; cy1[t] = Y1[ib + j];
            cx2[t] = X2[ib + j]; cy2[t] = Y2[ib + j];
            car[t] = AREA[ib + j];
        } else {
            cx1[t] = 0.f; cy1[t] = 0.f; cx2[t] = 0.f; cy2[t] = 0.f; car[t] = 0.f;
        }
    }
    __syncthreads();
    if (i >= TOPK) return;
    int ti = i >> 6;
    if (cb < ti) return;                     // sub-diagonal word: not stored
    unsigned long long w = 0;
    float vi = SC[ib + i];
    if (vi > 0.01f) {
        float rx1 = X1[ib + i], ry1 = Y1[ib + i];
        float rx2 = X2[ib + i], ry2 = Y2[ib + i];
        float ra = AREA[ib + i];
        #pragma unroll 4
        for (int jj = 0; jj < 64; ++jj) {
            int j = cb * 64 + jj;
            if (j <= i || j >= TOPK) continue;
            float dx = fminf(rx2, cx2[jj]) - fmaxf(rx1, cx1[jj]);
            float dy = fminf(ry2, cy2[jj]) - fmaxf(ry1, cy1[jj]);
            if (dx > 0.0f && dy > 0.0f) {
                float inter = dx * dy;
                float iou = inter / (car[jj] + ra - inter);  // (area_j+area_i)-inter
                if (iou > 0.3f) w |= (1ull << jj);
            }
        }
    }
    mask[(size_t)g * TRIW + (size_t)tri_base2(ti)
         + (size_t)(cb - ti) * 64 + (i & 63)] = w;
}

// K5b: register-resident blocked greedy scan. Thread (lw=tid>>2, qg=tid&3)
// owns rows qg*16..+15 of local word lw: 16 u64 = 128 B contiguous in the
// transposed slab; wave reads contiguous 8 KB. Per tile:
//   phase 1: prefetch tile t+1 into regs (all) + diag(t+1) (wave 0);
//            wave 0: rem |= prem(t-1), resolve tile t -> keepm;
//            waves 1-7: zero the other prem buffer
//   phase 2: masked-OR fold in regs -> 2 LDS atomicOr per active thread
// No LDS slab at all; prem double-buffered. One block per image.
__global__ void __launch_bounds__(512, 2) k_scan7(
        const float* __restrict__ SC, const float* __restrict__ X1,
        const float* __restrict__ Y1, const float* __restrict__ X2,
        const float* __restrict__ Y2,
        const unsigned long long* __restrict__ mask, float* __restrict__ out, int img0) {
    __shared__ unsigned prem32[2][160];          // [buf][2*word]: lo/hi halves
    __shared__ unsigned long long keepw[80];
    __shared__ unsigned pfx[80];
    __shared__ unsigned long long keepm_sh;
    int g = blockIdx.x;
    int img = img0 + g;
    int tid = threadIdx.x;
    int l = tid & 63;
    int wid = tid >> 6;
    size_t ib = (size_t)img * TOPK;
    const float* sc = SC + ib;
    const unsigned long long* mimg = mask + (size_t)g * TRIW;

    // wave-0 lane l owns removed-words l (rem0) and 64+l (rem1, l<15)
    unsigned long long rem0 = ~0ull, rem1 = ~0ull;
    if (wid == 0) {
        for (int w = 0; w < NWORDS; ++w) {
            int row = w * 64 + l;
            bool valid = (row < TOPK) && (sc[row] > 0.01f);
            unsigned long long b = __ballot(valid);
            if (l == w) rem0 = ~b;
            if (l == w - 64) rem1 = ~b;
        }
    }
    int lw = tid >> 2;                  // local word slot 0..127
    int qg = tid & 3;
    int rbase = qg * 16;
    if (tid < 160) { prem32[0][tid] = 0; prem32[1][tid] = 0; }

    // prologue: tile 0 values + diag into registers
    unsigned long long cur[16], nxt[16];
    unsigned long long diagC = 0, diagN = 0;
    if (lw < NWORDS) {
        const unsigned long long* p = mimg + (size_t)lw * 64 + rbase;
        #pragma unroll
        for (int r = 0; r < 16; ++r) cur[r] = p[r];
    }
    if (wid == 0) diagC = mimg[l];
    __syncthreads();

    for (int t = 0; t < NWORDS; ++t) {
        int s = NWORDS - t;
        int pOld = t & 1, pNew = pOld ^ 1;
        bool more = (t + 1 < NWORDS);
        // phase 1: prefetch t+1; wave 0 resolves t; waves 1-7 zero pNew
        if (more) {
            const unsigned long long* nb = mimg + tri_base2(t + 1);
            if (lw < s - 1) {
                const unsigned long long* p = nb + (size_t)lw * 64 + rbase;
                #pragma unroll
                for (int r = 0; r < 16; ++r) nxt[r] = p[r];
            }
            if (wid == 0) diagN = nb[l];
        }
        if (wid == 0) {
            if (t > 0) {
                int tp = t - 1;
                int c0 = l - tp;
                if (c0 >= 0)
                    rem0 |= ((unsigned long long)prem32[pOld][2 * c0 + 1] << 32)
                            | prem32[pOld][2 * c0];
                if (l < 15) {
                    int c1 = 64 + l - tp;
                    rem1 |= ((unsigned long long)prem32[pOld][2 * c1 + 1] << 32)
                            | prem32[pOld][2 * c1];
                }
            }
            unsigned long long remT = (t < 64) ? __shfl(rem0, t, 64)
                                               : __shfl(rem1, t - 64, 64);
            unsigned long long aliveInit = ~remT;
            bool meAlive = ((aliveInit >> l) & 1ull) != 0ull;
            unsigned long long dEff = diagC & aliveInit;
            unsigned long long sup = __ballot(meAlive && (dEff != 0ull));
            unsigned long long removed = remT;
            while (sup) {                       // usually empty or 1-3 rows
                int i = __builtin_ctzll(sup);
                sup &= sup - 1;
                if (!((removed >> i) & 1ull)) {
                    unsigned long long di = __shfl(diagC, i, 64);
                    removed |= di;              // di only has bits > i
                    sup &= ~di;
                }
            }
            unsigned long long keepm = ~removed;
            if (l == 0) { keepw[t] = keepm; keepm_sh = keepm; }
        } else {
            int z = tid - 64;
            if (z < 160) prem32[pNew][z] = 0;
        }
        __syncthreads();                        // keepm + zeroed pNew ready
        // phase 2: fold kept rows (registers) -> prem atomics
        {
            unsigned long long keepm = keepm_sh;
            if (lw < s) {
                unsigned long long acc = 0;
                #pragma unroll
                for (int r = 0; r < 16; ++r) {
                    unsigned long long m = 0ull -
                        ((keepm >> (rbase + r)) & 1ull);
                    acc |= cur[r] & m;
                }
                unsigned alo = (unsigned)acc;
                unsigned ahi = (unsigned)(acc >> 32);
                if (alo) atomicOr(&prem32[pNew][2 * lw], alo);
                if (ahi) atomicOr(&prem32[pNew][2 * lw + 1], ahi);
            }
        }
        if (more) {
            #pragma unroll
            for (int r = 0; r < 16; ++r) cur[r] = nxt[r];
            diagC = diagN;
        }
        __syncthreads();                        // pNew complete for t+1
    }

    if (tid == 0) {
        unsigned acc = 0;
        for (int w = 0; w < NWORDS; ++w) { pfx[w] = acc; acc += (unsigned)__popcll(keepw[w]); }
    }
    __syncthreads();

    const float* x1 = X1 + ib; const float* y1 = Y1 + ib;
    const float* x2 = X2 + ib; const float* y2 = Y2 + ib;
    float* op = out + (((size_t)img * 2) + 1) * TOPK * 5;
    for (int w = wid; w < NWORDS; w += 8) {
        unsigned long long kw = keepw[w];
        if (!kw) continue;
        int row = w * 64 + l;
        if ((kw >> l) & 1ull) {
            int rank = (int)pfx[w] + (int)__popcll(kw & ((1ull << l) - 1ull));
            float* r = op + (size_t)rank * 5;
            r[0] = sc[row]; r[1] = x1[row]; r[2] = y1[row];
            r[3] = x2[row]; r[4] = y2[row];
        }
    }
}

extern "C" void kernel_launch(void* const* d_in, const int* in_sizes, int n_in,
                              void* d_out, int out_size, void* d_ws, size_t ws_size,
                              hipStream_t stream) {
    (void)in_sizes; (void)n_in;
    const float* loc  = (const float*)d_in[0];   // (16, 136500, 4)
    const float* conf = (const float*)d_in[1];   // (16*136500, 2)
    const float* pri  = (const float*)d_in[2];   // (136500, 4)
    float* out = (float*)d_out;                  // (16, 2, 5000, 5)
    char* ws = (char*)d_ws;

    float* SC   = (float*)(ws + OFF_SC);
    float* X1   = (float*)(ws + OFF_X1);
    float* Y1   = (float*)(ws + OFF_Y1);
    float* X2   = (float*)(ws + OFF_X2);
    float* Y2   = (float*)(ws + OFF_Y2);
    float* AREA = (float*)(ws + OFF_AREA);
    unsigned* hist = (unsigned*)(ws + OFF_HIST);
    unsigned* cut  = (unsigned*)(ws + OFF_CUT);
    unsigned* gcnt = (unsigned*)(ws + OFF_GCNT);
    unsigned long long* keys = (unsigned long long*)(ws + OFF_KEYS);
    unsigned long long* mask = (unsigned long long*)(ws + OFF_MASK);

    hipMemsetAsync(d_out, 0, (size_t)out_size * sizeof(float), stream);
    hipMemsetAsync(ws + OFF_HIST, 0, 65536 + 64 + 2048, stream); // hist+cut+gcnt

    dim3 gh1(16, BNUM);                          // 16 grid-stride blocks/image
    k_hist<<<gh1, 256, 0, stream>>>(conf, hist);
    k_cutoff<<<BNUM, 256, 0, stream>>>(hist, cut);
    dim3 gh2((HPNUM + 255) / 256, BNUM);
    k_gather<<<gh2, 256, 0, stream>>>(conf, cut, gcnt, keys);
    // multi-block bitonic sort + parallel decode
    k_sloc1<<<BNUM * 4, 1024, 0, stream>>>(keys, gcnt);
    k_sloc2<<<BNUM * 2, 1024, 0, stream>>>(keys);
    k_sloc3<<<BNUM, 1024, 0, stream>>>(keys);
    k_decode<<<(BNUM * TOPK + 255) / 256, 256, 0, stream>>>(
        keys, loc, pri, SC, X1, Y1, X2, Y2, AREA);
    // hist/keys region now dead; mask may overwrite it.

    size_t avail = (ws_size > OFF_MASK) ? ws_size - OFF_MASK : 0;
    int gmax = (int)(avail / MASK_PER_IMG);
    if (gmax < 1) gmax = 1;
    if (gmax > BNUM) gmax = BNUM;
    int passes = (BNUM + gmax - 1) / gmax;
    int geach = (BNUM + passes - 1) / passes;   // even split across passes
    for (int i0 = 0; i0 < BNUM; i0 += geach) {
        int G = (BNUM - i0 < geach) ? (BNUM - i0) : geach;
        dim3 mg((TOPK + 255) / 256, NWORDS, G);
        k_mask<<<mg, 256, 0, stream>>>(SC, X1, Y1, X2, Y2, AREA, mask, i0);
        k_scan7<<<G, 512, 0, stream>>>(SC, X1, Y1, X2, Y2, mask, out, i0);
    }
}

// Round 13
// 386.353 us; speedup vs baseline: 1.0489x; 1.0489x over previous
//
#include <hip/hip_runtime.h>
#include <math.h>

#pragma clang fp contract(off)

// Problem constants (match reference)
#define PNUM 136500      // sum of f*f
#define HPNUM 68250      // PNUM/2 (exact)
#define BNUM 16
#define TOPK 5000
#define CAP 8192         // candidate capacity per image (power of 2 for bitonic)
#define NB2 1024         // histogram window buckets (covers ord16 of (0.01, 1.0))
#define B2BASE 0xBC00u   // window base: f2ord(0.01)>>16 = 0xBC23 >= 0xBC00
#define NWORDS 79        // ceil(5000/64)
#define TRIW 202240      // triangular words per image: 64 * (79+78+...+1)
#define MASK_PER_IMG ((size_t)TRIW * 8)   // 1,617,920 B
#define GSTRIDE 32       // gcnt padding: 32 u32 = 128 B per image

// Workspace layout (bytes). Boxes live at the front; hist/cut/gcnt/keys are
// DEAD after k_decode, so the mask region overlaps them.
#define OFF_SC    ((size_t)0)
#define OFF_X1    (OFF_SC + 320000)
#define OFF_Y1    (OFF_X1 + 320000)
#define OFF_X2    (OFF_Y1 + 320000)
#define OFF_Y2    (OFF_X2 + 320000)
#define OFF_AREA  (OFF_Y2 + 320000)       // ends at 1,920,000
#define OFF_MASK  ((size_t)1920000)
#define OFF_HIST  ((size_t)1920000)       // overlaps mask (dead before k_mask)
#define OFF_CUT   (OFF_HIST + 65536)      // hist = 16*1024*4 = 65536 B
#define OFF_GCNT  (OFF_CUT + 64)
#define OFF_KEYS  (OFF_GCNT + 2048)

__device__ __forceinline__ unsigned f2ord(float f) {
    unsigned u = __float_as_uint(f);
    return (u & 0x80000000u) ? ~u : (u | 0x80000000u);
}
__device__ __forceinline__ float ord2f(unsigned o) {
    unsigned u = (o & 0x80000000u) ? (o ^ 0x80000000u) : ~o;
    return __uint_as_float(u);
}
// word offset of block t's slab within an image's triangular mask (transposed:
// word w, row r at tri_base2(t) + (w-t)*64 + r)
__device__ __forceinline__ int tri_base2(int t) {
    return 64 * (79 * t - ((t * (t - 1)) >> 1));
}

// K1: per-image histogram over the 1024-bucket window in LDS, then one
// contiguous atomic merge per block.
__global__ void __launch_bounds__(256) k_hist(const float* __restrict__ conf,
                                              unsigned* __restrict__ hist) {
    __shared__ unsigned lh[NB2];
    int img = blockIdx.y;
    for (int i = threadIdx.x; i < NB2; i += 256) lh[i] = 0;
    __syncthreads();
    const float4* src = (const float4*)(conf + (size_t)img * PNUM * 2);
    int stride = gridDim.x * 256;
    for (int q = blockIdx.x * 256 + threadIdx.x; q < HPNUM; q += stride) {
        float4 v = src[q];
        if (v.y > 0.01f) atomicAdd(&lh[(f2ord(v.y) >> 16) - B2BASE], 1u);
        if (v.w > 0.01f) atomicAdd(&lh[(f2ord(v.w) >> 16) - B2BASE], 1u);
    }
    __syncthreads();
    unsigned* h = hist + (size_t)img * NB2;
    for (int i = threadIdx.x; i < NB2; i += 256) {
        unsigned c = lh[i];
        if (c) atomicAdd(&h[i], c);
    }
}

// K2: find cutoff (absolute 16-bit bucket) so count(bucket >= cut) >= TOPK
__global__ void __launch_bounds__(256) k_cutoff(const unsigned* __restrict__ hist,
                                                unsigned* __restrict__ cut) {
    __shared__ unsigned csum[256];
    int img = blockIdx.x;
    int t = threadIdx.x;
    const unsigned* h = hist + (size_t)img * NB2;
    unsigned s = 0;
    for (int b = 0; b < 4; ++b) s += h[t * 4 + b];
    csum[t] = s;
    __syncthreads();
    if (t == 0) {
        unsigned acc = 0, before = 0;
        int c = -1;
        for (int cc = 255; cc >= 0; --cc) {
            if (acc + csum[cc] >= (unsigned)TOPK) { c = cc; before = acc; break; }
            acc += csum[cc];
        }
        unsigned cutb = B2BASE;            // fallback: take all valid
        if (c >= 0) {
            unsigned s2 = before;
            cutb = B2BASE + (unsigned)c * 4u;
            for (int b = c * 4 + 3; b >= c * 4; --b) {
                s2 += h[b];
                if (s2 >= (unsigned)TOPK) { cutb = B2BASE + (unsigned)b; break; }
            }
        }
        cut[img] = cutb;
    }
}

// K3: gather candidate keys (ord<<32)|~p for buckets >= cutoff.
__global__ void __launch_bounds__(256) k_gather(
        const float* __restrict__ conf, const unsigned* __restrict__ cut,
        unsigned* __restrict__ gcnt, unsigned long long* __restrict__ keys) {
    __shared__ unsigned wbase[4];
    __shared__ unsigned bbase;
    int q = blockIdx.x * 256 + threadIdx.x;
    int img = blockIdx.y;
    int lane = threadIdx.x & 63, wid = threadIdx.x >> 6;
    unsigned cutb = cut[img];
    bool c0 = false, c1 = false;
    unsigned o0 = 0, o1 = 0;
    int p0 = 0, p1 = 0;
    if (q < HPNUM) {
        float4 v = ((const float4*)(conf + (size_t)img * PNUM * 2))[q];
        p0 = 2 * q; p1 = 2 * q + 1;
        if (v.y > 0.01f) { o0 = f2ord(v.y); c0 = (o0 >> 16) >= cutb; }
        if (v.w > 0.01f) { o1 = f2ord(v.w); c1 = (o1 >> 16) >= cutb; }
    }
    unsigned long long b0 = __ballot(c0), b1 = __ballot(c1);
    if (lane == 0) wbase[wid] = (unsigned)(__popcll(b0) + __popcll(b1));
    __syncthreads();
    if (threadIdx.x == 0) {
        unsigned t0 = wbase[0], t1 = wbase[1], t2 = wbase[2], t3 = wbase[3];
        unsigned tot = t0 + t1 + t2 + t3;
        unsigned base = tot ? atomicAdd(&gcnt[(size_t)img * GSTRIDE], tot) : 0u;
        bbase = base;
        wbase[0] = 0; wbase[1] = t0; wbase[2] = t0 + t1; wbase[3] = t0 + t1 + t2;
    }
    __syncthreads();
    unsigned mybase = bbase + wbase[wid];
    unsigned long long lt = (lane == 0) ? 0ull : ((1ull << lane) - 1ull);
    if (c0) {
        unsigned pos = mybase + (unsigned)__popcll(b0 & lt);
        if (pos < (unsigned)CAP)
            keys[(size_t)img * CAP + pos] =
                ((unsigned long long)o0 << 32) | (unsigned)(~(unsigned)p0);
    }
    if (c1) {
        unsigned pos = mybase + (unsigned)__popcll(b0) + (unsigned)__popcll(b1 & lt);
        if (pos < (unsigned)CAP)
            keys[(size_t)img * CAP + pos] =
                ((unsigned long long)o1 << 32) | (unsigned)(~(unsigned)p1);
    }
}

// ---- Multi-block bitonic sort of each image's 8192 keys (descending) ----

// K4a: stages k=2..2048 (all chunk-local). 4 chunks of 2048 per image.
__global__ void __launch_bounds__(1024) k_sloc1(
        unsigned long long* __restrict__ keys, const unsigned* __restrict__ gcnt) {
    __shared__ unsigned long long sk[2048];
    int img = blockIdx.x >> 2;
    int base = (blockIdx.x & 3) * 2048;
    int N = (int)min(gcnt[(size_t)img * GSTRIDE], (unsigned)CAP);
    unsigned long long* kp = keys + (size_t)img * CAP;
    int tid = threadIdx.x;
    for (int i = tid; i < 2048; i += 1024)
        sk[i] = (base + i < N) ? kp[base + i] : 0ull;
    __syncthreads();
    for (int k = 2; k <= 2048; k <<= 1) {
        for (int j = k >> 1; j > 0; j >>= 1) {
            int i = ((tid & ~(j - 1)) << 1) | (tid & (j - 1));
            int p = i | j;
            bool desc = (((base + i) & k) == 0);
            unsigned long long a = sk[i], b = sk[p];
            bool sw = desc ? (a < b) : (a > b);
            if (sw) { sk[i] = b; sk[p] = a; }
            __syncthreads();
        }
    }
    for (int i = tid; i < 2048; i += 1024) kp[base + i] = sk[i];
}

// K4b: stage k=4096 complete (j=2048..1). 2 half-spans of 4096 per image.
__global__ void __launch_bounds__(1024) k_sloc2(unsigned long long* __restrict__ keys) {
    __shared__ unsigned long long sk[4096];
    int img = blockIdx.x >> 1;
    int base = (blockIdx.x & 1) * 4096;
    unsigned long long* kp = keys + (size_t)img * CAP + base;
    int tid = threadIdx.x;
    for (int i = tid; i < 4096; i += 1024) sk[i] = kp[i];
    __syncthreads();
    for (int j = 2048; j > 0; j >>= 1) {
        for (int t = tid; t < 2048; t += 1024) {
            int i = ((t & ~(j - 1)) << 1) | (t & (j - 1));
            int p = i | j;
            bool desc = (((base + i) & 4096) == 0);
            unsigned long long a = sk[i], b = sk[p];
            bool sw = desc ? (a < b) : (a > b);
            if (sw) { sk[i] = b; sk[p] = a; }
        }
        __syncthreads();
    }
    for (int i = tid; i < 4096; i += 1024) kp[i] = sk[i];
}

// K4c: stage k=8192 complete (j=4096..1, all descending). 1 block per image.
__global__ void __launch_bounds__(1024) k_sloc3(unsigned long long* __restrict__ keys) {
    __shared__ unsigned long long sk[CAP];
    unsigned long long* kp = keys + (size_t)blockIdx.x * CAP;
    int tid = threadIdx.x;
    for (int i = tid; i < CAP; i += 1024) sk[i] = kp[i];
    __syncthreads();
    for (int j = 4096; j > 0; j >>= 1) {
        for (int t = tid; t < 4096; t += 1024) {
            int i = ((t & ~(j - 1)) << 1) | (t & (j - 1));
            int p = i | j;
            unsigned long long a = sk[i], b = sk[p];
            if (a < b) { sk[i] = b; sk[p] = a; }     // always descending
        }
        __syncthreads();
    }
    for (int i = tid; i < CAP; i += 1024) kp[i] = sk[i];
}

// K4d: decode sorted top-5000 keys -> SC/X1/Y1/X2/Y2/AREA (fully parallel)
__global__ void __launch_bounds__(256) k_decode(
        const unsigned long long* __restrict__ keys,
        const float* __restrict__ loc, const float* __restrict__ pri,
        float* __restrict__ SC, float* __restrict__ X1, float* __restrict__ Y1,
        float* __restrict__ X2, float* __restrict__ Y2, float* __restrict__ AREA) {
    int gidx = blockIdx.x * 256 + threadIdx.x;
    if (gidx >= BNUM * TOPK) return;
    int img = gidx / TOPK;
    int r = gidx - img * TOPK;
    unsigned long long key = keys[(size_t)img * CAP + r];
    size_t o = (size_t)img * TOPK + r;
    if (key != 0ull) {
        unsigned ordv = (unsigned)(key >> 32);
        float s = ord2f(ordv);
        unsigned p = ~(unsigned)(key & 0xFFFFFFFFull);
        const float* lp = loc + ((size_t)img * PNUM + p) * 4;
        const float* pp = pri + (size_t)p * 4;
        float lx = lp[0], ly = lp[1], lw = lp[2], lh = lp[3];
        float px = pp[0], py = pp[1], pw = pp[2], ph = pp[3];
        float cx = px + (lx * 0.1f) * pw;
        float cy = py + (ly * 0.1f) * ph;
        float w = pw * expf(lw * 0.2f);
        float h = ph * expf(lh * 0.2f);
        float x1 = cx - w * 0.5f;
        float y1 = cy - h * 0.5f;
        float x2 = x1 + w;
        float y2 = y1 + h;
        SC[o] = s; X1[o] = x1; Y1[o] = y1; X2[o] = x2; Y2[o] = y2;
        AREA[o] = (x2 - x1) * (y2 - y1);
    } else {
        SC[o] = -1.0f; X1[o] = 0.f; Y1[o] = 0.f; X2[o] = 0.f; Y2[o] = 0.f;
        AREA[o] = 0.f;
    }
}

// K5a: transposed triangular suppression mask. Bit jj of word w (row i,
// block t=i>>6) = 1 iff row i (valid) suppresses j=w*64+jj (j>i, iou>0.3).
__global__ void __launch_bounds__(256) k_mask(
        const float* __restrict__ SC, const float* __restrict__ X1,
        const float* __restrict__ Y1, const float* __restrict__ X2,
        const float* __restrict__ Y2, const float* __restrict__ AREA,
        unsigned long long* __restrict__ mask, int img0) {
    int g = blockIdx.z;
    int cb = blockIdx.y;
    int bx = blockIdx.x;
    if ((cb + 1) * 64 <= bx * 256) return;   // whole block strictly sub-diagonal
    __shared__ float cx1[64], cy1[64], cx2[64], cy2[64], car[64];
    int img = img0 + g;
    int i = bx * 256 + threadIdx.x;
    int t = threadIdx.x;
    size_t ib = (size_t)img * TOPK;
    if (t < 64) {
        int j = cb * 64 + t;
        if (j < TOPK) {
            cx1[t] = X1[ib + j]; cy1[t] = Y1[ib + j];
            cx2[t] = X2[ib + j]; cy2[t] = Y2[ib + j];
            car[t] = AREA[ib + j];
        } else {
            cx1[t] = 0.f; cy1[t] = 0.f; cx2[t] = 0.f; cy2[t] = 0.f; car[t] = 0.f;
        }
    }
    __syncthreads();
    if (i >= TOPK) return;
    int ti = i >> 6;
    if (cb < ti) return;                     // sub-diagonal word: not stored
    unsigned long long w = 0;
    float vi = SC[ib + i];
    if (vi > 0.01f) {
        float rx1 = X1[ib + i], ry1 = Y1[ib + i];
        float rx2 = X2[ib + i], ry2 = Y2[ib + i];
        float ra = AREA[ib + i];
        #pragma unroll 4
        for (int jj = 0; jj < 64; ++jj) {
            int j = cb * 64 + jj;
            if (j <= i || j >= TOPK) continue;
            float dx = fminf(rx2, cx2[jj]) - fmaxf(rx1, cx1[jj]);
            float dy = fminf(ry2, cy2[jj]) - fmaxf(ry1, cy1[jj]);
            if (dx > 0.0f && dy > 0.0f) {
                float inter = dx * dy;
                float iou = inter / (car[jj] + ra - inter);  // (area_j+area_i)-inter
                if (iou > 0.3f) w |= (1ull << jj);
            }
        }
    }
    mask[(size_t)g * TRIW + (size_t)tri_base2(ti)
         + (size_t)(cb - ti) * 64 + (i & 63)] = w;
}

// K5b: 2-deep-pipelined scan, replicated resolve, ONE barrier per tile.
// Buffers A/B/C hold tiles t%3; loads for t+2 issue at body(t) top and are
// first consumed at fold(t+2) -> ~2 iterations of latency slack, no register
// rotation. Every wave runs the identical resolve (deterministic), so keepm
// needs no publication; prem is plain double-buffered stores.
__global__ void __launch_bounds__(512, 2) k_scan8(
        const float* __restrict__ SC, const float* __restrict__ X1,
        const float* __restrict__ Y1, const float* __restrict__ X2,
        const float* __restrict__ Y2,
        const unsigned long long* __restrict__ mask, float* __restrict__ out, int img0) {
    __shared__ unsigned long long prem[2][4][80];
    __shared__ unsigned long long keepw[80];
    __shared__ unsigned pfx[80];
    int g = blockIdx.x;
    int img = img0 + g;
    int tid = threadIdx.x;
    int l = tid & 63;
    int wid = tid >> 6;
    size_t ib = (size_t)img * TOPK;
    const float* sc = SC + ib;
    const unsigned long long* mimg = mask + (size_t)g * TRIW;

    // replicated removed-state: every wave's lane l owns words l and 64+l
    unsigned long long rem0 = ~0ull, rem1 = ~0ull;
    for (int w = 0; w < NWORDS; ++w) {
        int row = w * 64 + l;
        bool valid = (row < TOPK) && (sc[row] > 0.01f);
        unsigned long long b = __ballot(valid);
        if (l == w) rem0 = ~b;
        if (l == w - 64) rem1 = ~b;
    }
    int lw = tid >> 2;                  // local word slot 0..127
    int qg = tid & 3;
    int rbase = qg * 16;

    unsigned long long A[16], B[16], C[16];
    unsigned long long dA = 0, dB = 0, dC = 0;
    // prologue: tile 0 -> A, tile 1 -> B
    if (lw < NWORDS) {
        const unsigned long long* p = mimg + (size_t)lw * 64 + rbase;
        #pragma unroll
        for (int r = 0; r < 16; ++r) A[r] = p[r];
    }
    dA = mimg[l];
    {
        const unsigned long long* nb = mimg + tri_base2(1);
        if (lw < NWORDS - 1) {
            const unsigned long long* p = nb + (size_t)lw * 64 + rbase;
            #pragma unroll
            for (int r = 0; r < 16; ++r) B[r] = p[r];
        }
        dB = nb[l];
    }

    auto body = [&](int t, unsigned long long (&cur)[16],
                    unsigned long long (&n2)[16],
                    unsigned long long dcur, unsigned long long& dn2) {
        int s = NWORDS - t;
        // issue loads for tile t+2 (consumed at fold(t+2), 2 iters away)
        if (t + 2 < NWORDS) {
            const unsigned long long* nb = mimg + tri_base2(t + 2);
            if (lw < s - 2) {
                const unsigned long long* p = nb + (size_t)lw * 64 + rbase;
                #pragma unroll
                for (int r = 0; r < 16; ++r) n2[r] = p[r];
            }
            dn2 = nb[l];
        }
        // replicated resolve of tile t (all waves, identical results)
        if (t > 0) {
            int tp = t - 1, pb = tp & 1;
            int c0 = l - tp;
            if (c0 >= 0)
                rem0 |= prem[pb][0][c0] | prem[pb][1][c0]
                      | prem[pb][2][c0] | prem[pb][3][c0];
            if (l < 15) {
                int c1 = 64 + l - tp;
                rem1 |= prem[pb][0][c1] | prem[pb][1][c1]
                      | prem[pb][2][c1] | prem[pb][3][c1];
            }
        }
        unsigned long long remT = (t < 64) ? __shfl(rem0, t, 64)
                                           : __shfl(rem1, t - 64, 64);
        unsigned long long aliveInit = ~remT;
        bool meAlive = ((aliveInit >> l) & 1ull) != 0ull;
        unsigned long long dEff = dcur & aliveInit;
        unsigned long long sup = __ballot(meAlive && (dEff != 0ull));
        unsigned long long removed = remT;
        while (sup) {                       // usually empty or 1-3 rows
            int i = __builtin_ctzll(sup);
            sup &= sup - 1;
            if (!((removed >> i) & 1ull)) {
                int iu = __builtin_amdgcn_readfirstlane(i);
                unsigned long long di = __shfl(dcur, iu, 64);
                removed |= di;              // di only has bits > i
                sup &= ~di;
            }
        }
        unsigned long long keepm = ~removed;
        if (tid == 0) keepw[t] = keepm;
        // fold kept rows (registers) -> prem plain store
        if (lw < s) {
            unsigned long long acc = 0;
            #pragma unroll
            for (int r = 0; r < 16; ++r) {
                unsigned long long m = 0ull - ((keepm >> (rbase + r)) & 1ull);
                acc |= cur[r] & m;
            }
            prem[t & 1][qg][lw] = acc;
        }
        __syncthreads();                    // prem(t) visible for resolve(t+1)
    };

    for (int t = 0; t < NWORDS; t += 3) {
        body(t, A, C, dA, dC);
        if (t + 1 < NWORDS) body(t + 1, B, A, dB, dA);
        if (t + 2 < NWORDS) body(t + 2, C, B, dC, dB);
    }

    if (tid == 0) {
        unsigned acc = 0;
        for (int w = 0; w < NWORDS; ++w) { pfx[w] = acc; acc += (unsigned)__popcll(keepw[w]); }
    }
    __syncthreads();

    const float* x1 = X1 + ib; const float* y1 = Y1 + ib;
    const float* x2 = X2 + ib; const float* y2 = Y2 + ib;
    float* op = out + (((size_t)img * 2) + 1) * TOPK * 5;
    for (int w = wid; w < NWORDS; w += 8) {
        unsigned long long kw = keepw[w];
        if (!kw) continue;
        int row = w * 64 + l;
        if ((kw >> l) & 1ull) {
            int rank = (int)pfx[w] + (int)__popcll(kw & ((1ull << l) - 1ull));
            float* r = op + (size_t)rank * 5;
            r[0] = sc[row]; r[1] = x1[row]; r[2] = y1[row];
            r[3] = x2[row]; r[4] = y2[row];
        }
    }
}

extern "C" void kernel_launch(void* const* d_in, const int* in_sizes, int n_in,
                              void* d_out, int out_size, void* d_ws, size_t ws_size,
                              hipStream_t stream) {
    (void)in_sizes; (void)n_in;
    const float* loc  = (const float*)d_in[0];   // (16, 136500, 4)
    const float* conf = (const float*)d_in[1];   // (16*136500, 2)
    const float* pri  = (const float*)d_in[2];   // (136500, 4)
    float* out = (float*)d_out;                  // (16, 2, 5000, 5)
    char* ws = (char*)d_ws;

    float* SC   = (float*)(ws + OFF_SC);
    float* X1   = (float*)(ws + OFF_X1);
    float* Y1   = (float*)(ws + OFF_Y1);
    float* X2   = (float*)(ws + OFF_X2);
    float* Y2   = (float*)(ws + OFF_Y2);
    float* AREA = (float*)(ws + OFF_AREA);
    unsigned* hist = (unsigned*)(ws + OFF_HIST);
    unsigned* cut  = (unsigned*)(ws + OFF_CUT);
    unsigned* gcnt = (unsigned*)(ws + OFF_GCNT);
    unsigned long long* keys = (unsigned long long*)(ws + OFF_KEYS);
    unsigned long long* mask = (unsigned long long*)(ws + OFF_MASK);

    hipMemsetAsync(d_out, 0, (size_t)out_size * sizeof(float), stream);
    hipMemsetAsync(ws + OFF_HIST, 0, 65536 + 64 + 2048, stream); // hist+cut+gcnt

    dim3 gh1(16, BNUM);                          // 16 grid-stride blocks/image
    k_hist<<<gh1, 256, 0, stream>>>(conf, hist);
    k_cutoff<<<BNUM, 256, 0, stream>>>(hist, cut);
    dim3 gh2((HPNUM + 255) / 256, BNUM);
    k_gather<<<gh2, 256, 0, stream>>>(conf, cut, gcnt, keys);
    // multi-block bitonic sort + parallel decode
    k_sloc1<<<BNUM * 4, 1024, 0, stream>>>(keys, gcnt);
    k_sloc2<<<BNUM * 2, 1024, 0, stream>>>(keys);
    k_sloc3<<<BNUM, 1024, 0, stream>>>(keys);
    k_decode<<<(BNUM * TOPK + 255) / 256, 256, 0, stream>>>(
        keys, loc, pri, SC, X1, Y1, X2, Y2, AREA);
    // hist/keys region now dead; mask may overwrite it.

    size_t avail = (ws_size > OFF_MASK) ? ws_size - OFF_MASK : 0;
    int gmax = (int)(avail / MASK_PER_IMG);
    if (gmax < 1) gmax = 1;
    if (gmax > BNUM) gmax = BNUM;
    int passes = (BNUM + gmax - 1) / gmax;
    int geach = (BNUM + passes - 1) / passes;   // even split across passes
    for (int i0 = 0; i0 < BNUM; i0 += geach) {
        int G = (BNUM - i0 < geach) ? (BNUM - i0) : geach;
        dim3 mg((TOPK + 255) / 256, NWORDS, G);
        k_mask<<<mg, 256, 0, stream>>>(SC, X1, Y1, X2, Y2, AREA, mask, i0);
        k_scan8<<<G, 512, 0, stream>>>(SC, X1, Y1, X2, Y2, mask, out, i0);
    }
}

// Round 14
// 320.680 us; speedup vs baseline: 1.2637x; 1.2048x over previous
//
#include <hip/hip_runtime.h>
#include <math.h>

#pragma clang fp contract(off)

// Problem constants (match reference)
#define PNUM 136500      // sum of f*f
#define HPNUM 68250      // PNUM/2 (exact)
#define BNUM 16
#define TOPK 5000
#define CAP 8192         // candidate capacity per image (power of 2 for bitonic)
#define NB2 1024         // histogram window buckets (covers ord16 of (0.01, 1.0))
#define B2BASE 0xBC00u   // window base: f2ord(0.01)>>16 = 0xBC23 >= 0xBC00
#define NWORDS 79        // ceil(5000/64)
#define GSTRIDE 32       // gcnt padding: 32 u32 = 128 B per image
#define CAPE 65536       // edge capacity per image (expected E ~ 1-3k)

// Workspace layout (bytes). Boxes at front; hist/cut/gcnt/keys dead after
// k_decode; edges/grouped written after.
#define OFF_SC    ((size_t)0)
#define OFF_X1    (OFF_SC + 320000)
#define OFF_Y1    (OFF_X1 + 320000)
#define OFF_X2    (OFF_Y1 + 320000)
#define OFF_Y2    (OFF_X2 + 320000)
#define OFF_AREA  (OFF_Y2 + 320000)       // ends at 1,920,000
#define OFF_HIST  ((size_t)1920000)       // 65536
#define OFF_CUT   (OFF_HIST + 65536)      // 64
#define OFF_GCNT  (OFF_CUT + 64)          // 2048
#define OFF_KEYS  (OFF_GCNT + 2048)       // 1,048,576 -> ends 3,036,224
#define OFF_ECNT  ((size_t)3036224)       // 2048
#define OFF_EDGE  ((size_t)3038272)       // 16*65536*4 = 4,194,304
#define OFF_GRP   (OFF_EDGE + 4194304)    // 4,194,304 -> ends 11,426,880

__device__ __forceinline__ unsigned f2ord(float f) {
    unsigned u = __float_as_uint(f);
    return (u & 0x80000000u) ? ~u : (u | 0x80000000u);
}
__device__ __forceinline__ float ord2f(unsigned o) {
    unsigned u = (o & 0x80000000u) ? (o ^ 0x80000000u) : ~o;
    return __uint_as_float(u);
}

// K1: per-image histogram over the 1024-bucket window in LDS, then one
// contiguous atomic merge per block.
__global__ void __launch_bounds__(256) k_hist(const float* __restrict__ conf,
                                              unsigned* __restrict__ hist) {
    __shared__ unsigned lh[NB2];
    int img = blockIdx.y;
    for (int i = threadIdx.x; i < NB2; i += 256) lh[i] = 0;
    __syncthreads();
    const float4* src = (const float4*)(conf + (size_t)img * PNUM * 2);
    int stride = gridDim.x * 256;
    for (int q = blockIdx.x * 256 + threadIdx.x; q < HPNUM; q += stride) {
        float4 v = src[q];
        if (v.y > 0.01f) atomicAdd(&lh[(f2ord(v.y) >> 16) - B2BASE], 1u);
        if (v.w > 0.01f) atomicAdd(&lh[(f2ord(v.w) >> 16) - B2BASE], 1u);
    }
    __syncthreads();
    unsigned* h = hist + (size_t)img * NB2;
    for (int i = threadIdx.x; i < NB2; i += 256) {
        unsigned c = lh[i];
        if (c) atomicAdd(&h[i], c);
    }
}

// K2: find cutoff (absolute 16-bit bucket) so count(bucket >= cut) >= TOPK
__global__ void __launch_bounds__(256) k_cutoff(const unsigned* __restrict__ hist,
                                                unsigned* __restrict__ cut) {
    __shared__ unsigned csum[256];
    int img = blockIdx.x;
    int t = threadIdx.x;
    const unsigned* h = hist + (size_t)img * NB2;
    unsigned s = 0;
    for (int b = 0; b < 4; ++b) s += h[t * 4 + b];
    csum[t] = s;
    __syncthreads();
    if (t == 0) {
        unsigned acc = 0, before = 0;
        int c = -1;
        for (int cc = 255; cc >= 0; --cc) {
            if (acc + csum[cc] >= (unsigned)TOPK) { c = cc; before = acc; break; }
            acc += csum[cc];
        }
        unsigned cutb = B2BASE;            // fallback: take all valid
        if (c >= 0) {
            unsigned s2 = before;
            cutb = B2BASE + (unsigned)c * 4u;
            for (int b = c * 4 + 3; b >= c * 4; --b) {
                s2 += h[b];
                if (s2 >= (unsigned)TOPK) { cutb = B2BASE + (unsigned)b; break; }
            }
        }
        cut[img] = cutb;
    }
}

// K3: gather candidate keys (ord<<32)|~p for buckets >= cutoff.
__global__ void __launch_bounds__(256) k_gather(
        const float* __restrict__ conf, const unsigned* __restrict__ cut,
        unsigned* __restrict__ gcnt, unsigned long long* __restrict__ keys) {
    __shared__ unsigned wbase[4];
    __shared__ unsigned bbase;
    int q = blockIdx.x * 256 + threadIdx.x;
    int img = blockIdx.y;
    int lane = threadIdx.x & 63, wid = threadIdx.x >> 6;
    unsigned cutb = cut[img];
    bool c0 = false, c1 = false;
    unsigned o0 = 0, o1 = 0;
    int p0 = 0, p1 = 0;
    if (q < HPNUM) {
        float4 v = ((const float4*)(conf + (size_t)img * PNUM * 2))[q];
        p0 = 2 * q; p1 = 2 * q + 1;
        if (v.y > 0.01f) { o0 = f2ord(v.y); c0 = (o0 >> 16) >= cutb; }
        if (v.w > 0.01f) { o1 = f2ord(v.w); c1 = (o1 >> 16) >= cutb; }
    }
    unsigned long long b0 = __ballot(c0), b1 = __ballot(c1);
    if (lane == 0) wbase[wid] = (unsigned)(__popcll(b0) + __popcll(b1));
    __syncthreads();
    if (threadIdx.x == 0) {
        unsigned t0 = wbase[0], t1 = wbase[1], t2 = wbase[2], t3 = wbase[3];
        unsigned tot = t0 + t1 + t2 + t3;
        unsigned base = tot ? atomicAdd(&gcnt[(size_t)img * GSTRIDE], tot) : 0u;
        bbase = base;
        wbase[0] = 0; wbase[1] = t0; wbase[2] = t0 + t1; wbase[3] = t0 + t1 + t2;
    }
    __syncthreads();
    unsigned mybase = bbase + wbase[wid];
    unsigned long long lt = (lane == 0) ? 0ull : ((1ull << lane) - 1ull);
    if (c0) {
        unsigned pos = mybase + (unsigned)__popcll(b0 & lt);
        if (pos < (unsigned)CAP)
            keys[(size_t)img * CAP + pos] =
                ((unsigned long long)o0 << 32) | (unsigned)(~(unsigned)p0);
    }
    if (c1) {
        unsigned pos = mybase + (unsigned)__popcll(b0) + (unsigned)__popcll(b1 & lt);
        if (pos < (unsigned)CAP)
            keys[(size_t)img * CAP + pos] =
                ((unsigned long long)o1 << 32) | (unsigned)(~(unsigned)p1);
    }
}

// ---- Multi-block bitonic sort of each image's 8192 keys (descending) ----

// K4a: stages k=2..2048 (all chunk-local). 4 chunks of 2048 per image.
__global__ void __launch_bounds__(1024) k_sloc1(
        unsigned long long* __restrict__ keys, const unsigned* __restrict__ gcnt) {
    __shared__ unsigned long long sk[2048];
    int img = blockIdx.x >> 2;
    int base = (blockIdx.x & 3) * 2048;
    int N = (int)min(gcnt[(size_t)img * GSTRIDE], (unsigned)CAP);
    unsigned long long* kp = keys + (size_t)img * CAP;
    int tid = threadIdx.x;
    for (int i = tid; i < 2048; i += 1024)
        sk[i] = (base + i < N) ? kp[base + i] : 0ull;
    __syncthreads();
    for (int k = 2; k <= 2048; k <<= 1) {
        for (int j = k >> 1; j > 0; j >>= 1) {
            int i = ((tid & ~(j - 1)) << 1) | (tid & (j - 1));
            int p = i | j;
            bool desc = (((base + i) & k) == 0);
            unsigned long long a = sk[i], b = sk[p];
            bool sw = desc ? (a < b) : (a > b);
            if (sw) { sk[i] = b; sk[p] = a; }
            __syncthreads();
        }
    }
    for (int i = tid; i < 2048; i += 1024) kp[base + i] = sk[i];
}

// K4b: stage k=4096 complete (j=2048..1). 2 half-spans of 4096 per image.
__global__ void __launch_bounds__(1024) k_sloc2(unsigned long long* __restrict__ keys) {
    __shared__ unsigned long long sk[4096];
    int img = blockIdx.x >> 1;
    int base = (blockIdx.x & 1) * 4096;
    unsigned long long* kp = keys + (size_t)img * CAP + base;
    int tid = threadIdx.x;
    for (int i = tid; i < 4096; i += 1024) sk[i] = kp[i];
    __syncthreads();
    for (int j = 2048; j > 0; j >>= 1) {
        for (int t = tid; t < 2048; t += 1024) {
            int i = ((t & ~(j - 1)) << 1) | (t & (j - 1));
            int p = i | j;
            bool desc = (((base + i) & 4096) == 0);
            unsigned long long a = sk[i], b = sk[p];
            bool sw = desc ? (a < b) : (a > b);
            if (sw) { sk[i] = b; sk[p] = a; }
        }
        __syncthreads();
    }
    for (int i = tid; i < 4096; i += 1024) kp[i] = sk[i];
}

// K4c: stage k=8192 complete (j=4096..1, all descending). 1 block per image.
__global__ void __launch_bounds__(1024) k_sloc3(unsigned long long* __restrict__ keys) {
    __shared__ unsigned long long sk[CAP];
    unsigned long long* kp = keys + (size_t)blockIdx.x * CAP;
    int tid = threadIdx.x;
    for (int i = tid; i < CAP; i += 1024) sk[i] = kp[i];
    __syncthreads();
    for (int j = 4096; j > 0; j >>= 1) {
        for (int t = tid; t < 4096; t += 1024) {
            int i = ((t & ~(j - 1)) << 1) | (t & (j - 1));
            int p = i | j;
            unsigned long long a = sk[i], b = sk[p];
            if (a < b) { sk[i] = b; sk[p] = a; }     // always descending
        }
        __syncthreads();
    }
    for (int i = tid; i < CAP; i += 1024) kp[i] = sk[i];
}

// K4d: decode sorted top-5000 keys -> SC/X1/Y1/X2/Y2/AREA (fully parallel)
__global__ void __launch_bounds__(256) k_decode(
        const unsigned long long* __restrict__ keys,
        const float* __restrict__ loc, const float* __restrict__ pri,
        float* __restrict__ SC, float* __restrict__ X1, float* __restrict__ Y1,
        float* __restrict__ X2, float* __restrict__ Y2, float* __restrict__ AREA) {
    int gidx = blockIdx.x * 256 + threadIdx.x;
    if (gidx >= BNUM * TOPK) return;
    int img = gidx / TOPK;
    int r = gidx - img * TOPK;
    unsigned long long key = keys[(size_t)img * CAP + r];
    size_t o = (size_t)img * TOPK + r;
    if (key != 0ull) {
        unsigned ordv = (unsigned)(key >> 32);
        float s = ord2f(ordv);
        unsigned p = ~(unsigned)(key & 0xFFFFFFFFull);
        const float* lp = loc + ((size_t)img * PNUM + p) * 4;
        const float* pp = pri + (size_t)p * 4;
        float lx = lp[0], ly = lp[1], lw = lp[2], lh = lp[3];
        float px = pp[0], py = pp[1], pw = pp[2], ph = pp[3];
        float cx = px + (lx * 0.1f) * pw;
        float cy = py + (ly * 0.1f) * ph;
        float w = pw * expf(lw * 0.2f);
        float h = ph * expf(lh * 0.2f);
        float x1 = cx - w * 0.5f;
        float y1 = cy - h * 0.5f;
        float x2 = x1 + w;
        float y2 = y1 + h;
        SC[o] = s; X1[o] = x1; Y1[o] = y1; X2[o] = x2; Y2[o] = y2;
        AREA[o] = (x2 - x1) * (y2 - y1);
    } else {
        SC[o] = -1.0f; X1[o] = 0.f; Y1[o] = 0.f; X2[o] = 0.f; Y2[o] = 0.f;
        AREA[o] = 0.f;
    }
}

// K5a: SPARSE suppression edges. Same IoU tiling/arithmetic as the dense
// mask; on hit emits edge (victim j << 13 | suppressor i), j > i. Early-out
// overlap test gates the IEEE division (exact: no overlap => iou=0).
__global__ void __launch_bounds__(256) k_mask2(
        const float* __restrict__ SC, const float* __restrict__ X1,
        const float* __restrict__ Y1, const float* __restrict__ X2,
        const float* __restrict__ Y2, const float* __restrict__ AREA,
        unsigned* __restrict__ ecnt, unsigned* __restrict__ edges) {
    int img = blockIdx.z;
    int cb = blockIdx.y;
    int bx = blockIdx.x;
    if ((cb + 1) * 64 <= bx * 256) return;   // whole block strictly sub-diagonal
    __shared__ float cx1[64], cy1[64], cx2[64], cy2[64], car[64];
    int i = bx * 256 + threadIdx.x;
    int t = threadIdx.x;
    size_t ib = (size_t)img * TOPK;
    if (t < 64) {
        int j = cb * 64 + t;
        if (j < TOPK) {
            cx1[t] = X1[ib + j]; cy1[t] = Y1[ib + j];
            cx2[t] = X2[ib + j]; cy2[t] = Y2[ib + j];
            car[t] = AREA[ib + j];
        } else {
            cx1[t] = 0.f; cy1[t] = 0.f; cx2[t] = 0.f; cy2[t] = 0.f; car[t] = 0.f;
        }
    }
    __syncthreads();
    if (i >= TOPK) return;
    if (cb < (i >> 6)) return;               // entire column block <= i
    float vi = SC[ib + i];
    if (!(vi > 0.01f)) return;
    float rx1 = X1[ib + i], ry1 = Y1[ib + i];
    float rx2 = X2[ib + i], ry2 = Y2[ib + i];
    float ra = AREA[ib + i];
    unsigned* ec = ecnt + (size_t)img * GSTRIDE;
    unsigned* ei = edges + (size_t)img * CAPE;
    #pragma unroll 4
    for (int jj = 0; jj < 64; ++jj) {
        int j = cb * 64 + jj;
        if (j <= i || j >= TOPK) continue;
        float dx = fminf(rx2, cx2[jj]) - fmaxf(rx1, cx1[jj]);
        float dy = fminf(ry2, cy2[jj]) - fmaxf(ry1, cy1[jj]);
        if (dx > 0.0f && dy > 0.0f) {
            float inter = dx * dy;
            float iou = inter / (car[jj] + ra - inter);  // (area_j+area_i)-inter
            if (iou > 0.3f) {
                unsigned pos = atomicAdd(ec, 1u);
                if (pos < (unsigned)CAPE)
                    ei[pos] = ((unsigned)j << 13) | (unsigned)i;
            }
        }
    }
}

// K5b: sparse greedy resolve + compaction. One block (256) per image.
//  A) bucket edges by victim tile (79 buckets, counting sort)
//  B) wave 0: per tile, aggregate in-tile suppressor words + cross-tile
//     removals (checked against finalized keep bits), then exact ascending
//     ctz/ballot mini-loop; keepw[t] = survivors
//  C) all threads: prefix + compacted output write
__global__ void __launch_bounds__(256) k_nms2(
        const float* __restrict__ SC, const float* __restrict__ X1,
        const float* __restrict__ Y1, const float* __restrict__ X2,
        const float* __restrict__ Y2,
        const unsigned* __restrict__ ecnt, const unsigned* __restrict__ edges,
        unsigned* __restrict__ grouped, float* __restrict__ out) {
    __shared__ unsigned cnt[80], ofs[80], cur[80];
    __shared__ unsigned long long keepw[80];
    __shared__ unsigned pfx[80];
    __shared__ unsigned inLo[64], inHi[64];
    __shared__ unsigned remS[2];
    int img = blockIdx.x;
    int tid = threadIdx.x;
    int l = tid & 63;
    int wid = tid >> 6;
    size_t ib = (size_t)img * TOPK;
    const float* sc = SC + ib;

    // A: counting sort of edges by victim tile (v>>6 == edge>>19)
    if (tid < 80) cnt[tid] = 0;
    __syncthreads();
    unsigned E = min(ecnt[(size_t)img * GSTRIDE], (unsigned)CAPE);
    const unsigned* eimg = edges + (size_t)img * CAPE;
    unsigned* gimg = grouped + (size_t)img * CAPE;
    for (unsigned e = tid; e < E; e += 256) atomicAdd(&cnt[eimg[e] >> 19], 1u);
    __syncthreads();
    if (tid == 0) {
        unsigned a = 0;
        for (int w = 0; w < NWORDS; ++w) { ofs[w] = a; a += cnt[w]; }
    }
    __syncthreads();
    if (tid < 80) cur[tid] = ofs[tid];
    __syncthreads();
    for (unsigned e = tid; e < E; e += 256) {
        unsigned ed = eimg[e];
        unsigned p = atomicAdd(&cur[ed >> 19], 1u);
        gimg[p] = ed;
    }
    __syncthreads();

    // B: wave-0 serial-over-tiles resolve
    if (wid == 0) {
        for (int t = 0; t < NWORDS; ++t) {
            inLo[l] = 0; inHi[l] = 0;
            if (l < 2) remS[l] = 0;
            int row = t * 64 + l;
            bool valid = (row < TOPK) && (sc[row] > 0.01f);
            unsigned c = cnt[t], o = ofs[t];
            for (unsigned k = l; k < c; k += 64) {
                unsigned ed = gimg[o + k];
                unsigned v = ed >> 13, s = ed & 8191u;
                unsigned vb = v & 63u, sb = s & 63u;
                int st = (int)(s >> 6);
                if (st == t) {
                    if (sb < 32) atomicOr(&inLo[vb], 1u << sb);
                    else         atomicOr(&inHi[vb], 1u << (sb - 32));
                } else {
                    unsigned long long kw = keepw[st];   // finalized (st < t)
                    if ((kw >> sb) & 1ull) {
                        if (vb < 32) atomicOr(&remS[0], 1u << vb);
                        else         atomicOr(&remS[1], 1u << (vb - 32));
                    }
                }
            }
            __builtin_amdgcn_s_waitcnt(0);   // drain LDS atomics before reads
            unsigned long long inW =
                ((unsigned long long)inHi[l] << 32) | inLo[l];
            unsigned long long remW =
                ((unsigned long long)remS[1] << 32) | remS[0];
            bool alive = valid && !((remW >> l) & 1ull);
            while (true) {                   // exact ascending greedy
                unsigned long long aliveW = __ballot(alive);
                unsigned long long pend =
                    __ballot(alive && ((inW & aliveW) != 0ull));
                if (!pend) break;
                int v = __builtin_ctzll(pend);
                if (l == v) alive = false;
            }
            unsigned long long kwv = __ballot(alive);
            if (l == 0) keepw[t] = kwv;
        }
    }
    __syncthreads();

    // C: prefix + compacted output write
    if (tid == 0) {
        unsigned acc = 0;
        for (int w = 0; w < NWORDS; ++w) { pfx[w] = acc; acc += (unsigned)__popcll(keepw[w]); }
    }
    __syncthreads();
    const float* x1 = X1 + ib; const float* y1 = Y1 + ib;
    const float* x2 = X2 + ib; const float* y2 = Y2 + ib;
    float* op = out + (((size_t)img * 2) + 1) * TOPK * 5;
    for (int w = wid; w < NWORDS; w += 4) {
        unsigned long long kw = keepw[w];
        if (!kw) continue;
        int row = w * 64 + l;
        if ((kw >> l) & 1ull) {
            int rank = (int)pfx[w] + (int)__popcll(kw & ((1ull << l) - 1ull));
            float* r = op + (size_t)rank * 5;
            r[0] = sc[row]; r[1] = x1[row]; r[2] = y1[row];
            r[3] = x2[row]; r[4] = y2[row];
        }
    }
}

extern "C" void kernel_launch(void* const* d_in, const int* in_sizes, int n_in,
                              void* d_out, int out_size, void* d_ws, size_t ws_size,
                              hipStream_t stream) {
    (void)in_sizes; (void)n_in; (void)ws_size;
    const float* loc  = (const float*)d_in[0];   // (16, 136500, 4)
    const float* conf = (const float*)d_in[1];   // (16*136500, 2)
    const float* pri  = (const float*)d_in[2];   // (136500, 4)
    float* out = (float*)d_out;                  // (16, 2, 5000, 5)
    char* ws = (char*)d_ws;

    float* SC   = (float*)(ws + OFF_SC);
    float* X1   = (float*)(ws + OFF_X1);
    float* Y1   = (float*)(ws + OFF_Y1);
    float* X2   = (float*)(ws + OFF_X2);
    float* Y2   = (float*)(ws + OFF_Y2);
    float* AREA = (float*)(ws + OFF_AREA);
    unsigned* hist = (unsigned*)(ws + OFF_HIST);
    unsigned* cut  = (unsigned*)(ws + OFF_CUT);
    unsigned* gcnt = (unsigned*)(ws + OFF_GCNT);
    unsigned long long* keys = (unsigned long long*)(ws + OFF_KEYS);
    unsigned* ecnt = (unsigned*)(ws + OFF_ECNT);
    unsigned* edges = (unsigned*)(ws + OFF_EDGE);
    unsigned* grouped = (unsigned*)(ws + OFF_GRP);

    hipMemsetAsync(d_out, 0, (size_t)out_size * sizeof(float), stream);
    // zero hist+cut+gcnt (+keys harmlessly) + ecnt in one contiguous range
    hipMemsetAsync(ws + OFF_HIST, 0, (OFF_ECNT + 2048) - OFF_HIST, stream);

    dim3 gh1(16, BNUM);                          // 16 grid-stride blocks/image
    k_hist<<<gh1, 256, 0, stream>>>(conf, hist);
    k_cutoff<<<BNUM, 256, 0, stream>>>(hist, cut);
    dim3 gh2((HPNUM + 255) / 256, BNUM);
    k_gather<<<gh2, 256, 0, stream>>>(conf, cut, gcnt, keys);
    // multi-block bitonic sort + parallel decode
    k_sloc1<<<BNUM * 4, 1024, 0, stream>>>(keys, gcnt);
    k_sloc2<<<BNUM * 2, 1024, 0, stream>>>(keys);
    k_sloc3<<<BNUM, 1024, 0, stream>>>(keys);
    k_decode<<<(BNUM * TOPK + 255) / 256, 256, 0, stream>>>(
        keys, loc, pri, SC, X1, Y1, X2, Y2, AREA);

    // sparse NMS: edge emission (all 16 images, one pass) + resolve
    dim3 mg((TOPK + 255) / 256, NWORDS, BNUM);
    k_mask2<<<mg, 256, 0, stream>>>(SC, X1, Y1, X2, Y2, AREA, ecnt, edges);
    k_nms2<<<BNUM, 256, 0, stream>>>(SC, X1, Y1, X2, Y2, ecnt, edges, grouped, out);
}